// Round 4
// baseline (732.117 us; speedup 1.0000x reference)
//
#include <hip/hip_runtime.h>
#include <hip/hip_bf16.h>
#include <cstdint>
#include <cstddef>

typedef __bf16 bf16_t;
typedef __bf16 bf16x8 __attribute__((ext_vector_type(8)));
typedef __bf16 bf16x4 __attribute__((ext_vector_type(4)));
typedef float f32x4 __attribute__((ext_vector_type(4)));

#define MFMA16(a, b, c) __builtin_amdgcn_mfma_f32_16x16x32_bf16((a), (b), (c), 0, 0, 0)

__device__ __forceinline__ void gload_lds16(const void* g, void* l) {
  __builtin_amdgcn_global_load_lds((__attribute__((address_space(1))) void*)(g),
                                   (__attribute__((address_space(3))) void*)(l),
                                   16, 0, 0);
}

__device__ __forceinline__ uint32_t pkbf(float lo, float hi) {
  union { bf16_t h[2]; uint32_t u; } u2;
  u2.h[0] = (bf16_t)lo; u2.h[1] = (bf16_t)hi;
  return u2.u;
}

// ---------------------------------------------------------------- cvt x fp32->bf16
__global__ __launch_bounds__(256) void cvt_f32_to_bf16(const float* __restrict__ in,
                                                       bf16_t* __restrict__ out) {
  size_t i = ((size_t)blockIdx.x * 256 + threadIdx.x) * 4;
  float4 v = *(const float4*)(in + i);
  bf16x4 o = {(bf16_t)v.x, (bf16_t)v.y, (bf16_t)v.z, (bf16_t)v.w};
  *(bf16x4*)(out + i) = o;
}

// ---------------------------------------------------------------- weight transpose fp32 (R,C) -> bf16 (C,R)
__global__ __launch_bounds__(256) void transpose_w(const float* __restrict__ in,
                                                   bf16_t* __restrict__ out, int R, int C) {
  __shared__ bf16_t tile[32][33];
  int c0 = blockIdx.x * 32, r0 = blockIdx.y * 32;
  int tx = threadIdx.x, ty = threadIdx.y;
#pragma unroll
  for (int s = 0; s < 4; s++) {
    int r = ty + s * 8;
    tile[r][tx] = (bf16_t)in[(size_t)(r0 + r) * C + c0 + tx];
  }
  __syncthreads();
#pragma unroll
  for (int s = 0; s < 4; s++) {
    int r = ty + s * 8;
    out[(size_t)(c0 + r) * R + r0 + tx] = tile[tx][r];
  }
}

// ---------------------------------------------------------------- v (4096,3072) -> vt (b,h,192,2048)
__global__ __launch_bounds__(256) void transpose_v_kernel(const bf16_t* __restrict__ v,
                                                          bf16_t* __restrict__ vt) {
  __shared__ bf16_t tile[32][33];
  int bh = blockIdx.z;
  int t0 = blockIdx.x * 32, d0 = blockIdx.y * 32;
  int tx = threadIdx.x, ty = threadIdx.y;
  const bf16_t* src = v + (size_t)(bh >> 4) * 2048 * 3072 + (bh & 15) * 192;
#pragma unroll
  for (int s = 0; s < 4; s++) {
    int t = ty + s * 8;
    tile[t][tx] = src[(size_t)(t0 + t) * 3072 + d0 + tx];
  }
  __syncthreads();
  bf16_t* dst = vt + (size_t)bh * 192 * 2048;
#pragma unroll
  for (int s = 0; s < 4; s++) {
    int d = ty + s * 8;
    dst[(size_t)(d0 + d) * 2048 + t0 + tx] = tile[tx][d];
  }
}

// ---------------------------------------------------------------- rope in-place on packed (4096, 16*192) buffer
__global__ __launch_bounds__(256) void rope_inplace(bf16_t* __restrict__ buf) {
  int idx = blockIdx.x * 256 + threadIdx.x;
  int j = idx & 31;
  int h = (idx >> 5) & 15;
  int row = idx >> 9;           // 0..4095
  int t = row & 2047;
  size_t base = (size_t)row * 3072 + h * 192 + 128;
  float inv = expf(-(float)j * 0.28782313662425574f);
  float ang = (float)t * inv;
  float c, s;
  sincosf(ang, &s, &c);
  float x1 = (float)buf[base + j];
  float x2 = (float)buf[base + j + 32];
  buf[base + j]      = (bf16_t)(x1 * c - x2 * s);
  buf[base + j + 32] = (bf16_t)(x1 * s + x2 * c);
}

// ---------------------------------------------------------------- GEMM: C = A(M,lda) [:, :K] * Bt(N,K)^T
template <int MODE>
__global__ __launch_bounds__(256) void gemm_bt(const bf16_t* __restrict__ A, int lda,
                                               const bf16_t* __restrict__ Bt,
                                               void* __restrict__ C0, void* __restrict__ C1,
                                               void* __restrict__ C2, int K, int ldc) {
  __shared__ __align__(16) bf16_t sA[128 * 64];
  __shared__ __align__(16) bf16_t sB[128 * 64];
  const int tid = threadIdx.x;
  const int l = tid & 63, w = tid >> 6;
  const int l15 = l & 15, l4 = l >> 4;
  const int wr = w >> 1, wc = w & 1;
  const int m0 = blockIdx.y * 128, n0 = blockIdx.x * 128;

  f32x4 acc[4][4] = {};

  for (int kt = 0; kt < K; kt += 64) {
#pragma unroll
    for (int r = 0; r < 4; r++) {
      int i = r * 256 + tid;
      int row = i >> 3, cl = i & 7;
      int cg = cl ^ (row & 7);  // pre-swizzled global source, linear LDS dest
      const bf16_t* srcA = A + (size_t)(m0 + row) * lda + kt + cg * 8;
      const bf16_t* srcB = Bt + (size_t)(n0 + row) * K + kt + cg * 8;
      char* dstA = (char*)sA + (size_t)(r * 256 + w * 64) * 16;
      char* dstB = (char*)sB + (size_t)(r * 256 + w * 64) * 16;
      gload_lds16(srcA, dstA);
      gload_lds16(srcB, dstB);
    }
    __syncthreads();
#pragma unroll
    for (int ks = 0; ks < 2; ks++) {
      bf16x8 af[4], bfr[4];
#pragma unroll
      for (int mf = 0; mf < 4; mf++) {
        int row = wr * 64 + mf * 16 + l15;
        int cl = (ks * 4 + l4) ^ (row & 7);
        af[mf] = *(const bf16x8*)(sA + row * 64 + cl * 8);
      }
#pragma unroll
      for (int nf = 0; nf < 4; nf++) {
        int row = wc * 64 + nf * 16 + l15;
        int cl = (ks * 4 + l4) ^ (row & 7);
        bfr[nf] = *(const bf16x8*)(sB + row * 64 + cl * 8);
      }
#pragma unroll
      for (int mf = 0; mf < 4; mf++)
#pragma unroll
        for (int nf = 0; nf < 4; nf++)
          acc[mf][nf] = MFMA16(af[mf], bfr[nf], acc[mf][nf]);
    }
    __syncthreads();
  }

#pragma unroll
  for (int mf = 0; mf < 4; mf++)
#pragma unroll
    for (int nf = 0; nf < 4; nf++)
#pragma unroll
      for (int r = 0; r < 4; r++) {
        int m = m0 + wr * 64 + mf * 16 + l4 * 4 + r;
        int n = n0 + wc * 64 + nf * 16 + l15;
        float v = acc[mf][nf][r];
        if constexpr (MODE == 1) {
          ((float*)C0)[(size_t)m * ldc + n] = v;
        } else if constexpr (MODE == 2) {
          ((bf16_t*)C0)[(size_t)m * 3072 + (n >> 7) * 192 + (n & 127)] = (bf16_t)v;
        } else if constexpr (MODE == 4) {
          if (n < 1280) {
            ((bf16_t*)C0)[(size_t)m * 1280 + n] = (bf16_t)v;
          } else if (n < 2304) {
            int nn = n - 1280;
            ((bf16_t*)C1)[(size_t)m * 3072 + (nn >> 6) * 192 + 128 + (nn & 63)] = (bf16_t)v;
          } else {
            int nn = n - 2304;
            ((bf16_t*)C2)[(size_t)m * 3072 + (nn >> 6) * 192 + 128 + (nn & 63)] = (bf16_t)v;
          }
        } else {  // MODE 5
          if (n < 2048) {
            ((bf16_t*)C0)[(size_t)m * 3072 + (n >> 7) * 192 + (n & 127)] = (bf16_t)v;
          } else {
            ((bf16_t*)C1)[(size_t)m * 3072 + (n - 2048)] = (bf16_t)v;
          }
        }
      }
}

// ---------------------------------------------------------------- flash attention (causal, paired chunks)
// Swapped QK^T (lane-local softmax) + register prefetch of next K/V tile (T14):
// issue 12x dwordx4 loads at loop top, compute current tile from LDS, barrier,
// ds_write_b128 the prefetched tile, barrier. Complementary-p block pairing.
__global__ __launch_bounds__(256) void attn_kernel(const bf16_t* __restrict__ q,
                                                   const bf16_t* __restrict__ kbuf,
                                                   const bf16_t* __restrict__ vt,
                                                   bf16_t* __restrict__ ao) {
  __shared__ __align__(16) bf16_t sK[64][192];  // perm-24 swizzle
  __shared__ __align__(16) bf16_t sV[192][64];  // xor-8 chunk swizzle

  const int tid = threadIdx.x, l = tid & 63, w = tid >> 6;
  const int l15 = l & 15, l4 = (l >> 4) & 3;
  // block remap: c and c+256 land on the same CU (round-robin) -> give them
  // complementary p so per-CU iteration totals are uniform (49 tile-units).
  const int c = blockIdx.x;
  const int half = c >> 8, idx = c & 255;
  const int bh = (idx >> 4) + half * 16;
  const int pp = idx & 15;
  const int p = half ? 15 - pp : pp;
  const int b = bh >> 4, h = bh & 15;
  const int ca = p, cb = 31 - p;
  const int ra = ca * 64 + w * 16;
  const int rb = cb * 64 + w * 16;

  const bf16_t* qp = q + (size_t)b * 2048 * 3072 + h * 192;
  const bf16_t* kp = kbuf + (size_t)b * 2048 * 3072 + h * 192;
  const bf16_t* vp = vt + (size_t)bh * 192 * 2048;

  bf16x8 qf[2][6];
#pragma unroll
  for (int kd = 0; kd < 6; kd++) {
    qf[0][kd] = *(const bf16x8*)(qp + (size_t)(ra + l15) * 3072 + kd * 32 + l4 * 8);
    qf[1][kd] = *(const bf16x8*)(qp + (size_t)(rb + l15) * 3072 + kd * 32 + l4 * 8);
  }

  f32x4 o[2][12] = {};
  float mrow[2] = {-__builtin_inff(), -__builtin_inff()};
  float lrow[2] = {0.0f, 0.0f};

  const float scale = 0.07216878364870322f;  // 1/sqrt(192)
  const float THR = 7.0f;                    // defer-max threshold
  const int nkt = cb + 1;
  const int src0 = l15 + ((l4 & 1) << 5);
  const int src1 = src0 + 16;
  const bool hibank = (l4 & 2) != 0;

  uint4 gk[6], gv[6];
  // prefetch issue: same global addresses gload_lds used (pre-swizzled source)
#define ISSUE_LOADS(K0N)                                                        \
  {                                                                             \
    _Pragma("unroll")                                                           \
    for (int r = 0; r < 6; r++) {                                               \
      int i = r * 256 + tid;                                                    \
      int row = i / 24, cc = i % 24;                                            \
      int g = cc - (row & 7) * 3;                                               \
      if (g < 0) g += 24;                                                       \
      gk[r] = *(const uint4*)(kp + (size_t)((K0N) + row) * 3072 + g * 8);       \
    }                                                                           \
    _Pragma("unroll")                                                           \
    for (int r = 0; r < 6; r++) {                                               \
      int i = r * 256 + tid;                                                    \
      int d = i >> 3, cc = i & 7;                                               \
      gv[r] = *(const uint4*)(vp + (size_t)d * 2048 + (K0N) + (cc ^ (d & 7)) * 8); \
    }                                                                           \
  }
#define WRITE_TILES()                                                           \
  {                                                                             \
    _Pragma("unroll")                                                           \
    for (int r = 0; r < 6; r++) {                                               \
      *(uint4*)((char*)sK + (size_t)(r * 256 + tid) * 16) = gk[r];              \
      *(uint4*)((char*)sV + (size_t)(r * 256 + tid) * 16) = gv[r];              \
    }                                                                           \
  }

  ISSUE_LOADS(0)
  WRITE_TILES()
  __syncthreads();

  for (int kt = 0; kt < nkt; kt++) {
    const int k0 = kt * 64;
    const bool act_a = (kt <= ca);
    const bool pf = (kt + 1 < nkt);
    if (pf) ISSUE_LOADS(k0 + 64)

    // S^T = K Q^T  (swapped operands)
    f32x4 s[2][4] = {};
#pragma unroll
    for (int kd = 0; kd < 6; kd++) {
      bf16x8 bk[4];
#pragma unroll
      for (int nf = 0; nf < 4; nf++) {
        int row = nf * 16 + l15;
        int cl = kd * 4 + l4 + (row & 7) * 3;
        if (cl >= 24) cl -= 24;
        bk[nf] = *(const bf16x8*)(&sK[row][cl * 8]);
      }
#pragma unroll
      for (int nf = 0; nf < 4; nf++)
        s[1][nf] = MFMA16(bk[nf], qf[1][kd], s[1][nf]);
      if (act_a) {
#pragma unroll
        for (int nf = 0; nf < 4; nf++)
          s[0][nf] = MFMA16(bk[nf], qf[0][kd], s[0][nf]);
      }
    }

    bf16x8 pa[2][2] = {};

#define SOFTMAX_CHUNK(c, rbase, cid)                                                   \
    {                                                                                  \
      const bool diag = (kt == (cid));                                                 \
      _Pragma("unroll")                                                                \
      for (int nf = 0; nf < 4; nf++)                                                   \
        _Pragma("unroll")                                                              \
        for (int r = 0; r < 4; r++) {                                                  \
          float sv = s[c][nf][r] * scale;                                              \
          if (diag) {                                                                  \
            int ktok = k0 + nf * 16 + l4 * 4 + r;                                      \
            if (ktok > (rbase) + l15) sv = -__builtin_inff();                          \
          }                                                                            \
          s[c][nf][r] = sv;                                                            \
        }                                                                              \
      float m_in = s[c][0][0];                                                         \
      _Pragma("unroll")                                                                \
      for (int nf = 0; nf < 4; nf++)                                                   \
        _Pragma("unroll")                                                              \
        for (int r = 0; r < 4; r++)                                                    \
          if (nf | r) m_in = fmaxf(m_in, s[c][nf][r]);                                 \
      m_in = fmaxf(m_in, __shfl_xor(m_in, 16));                                        \
      m_in = fmaxf(m_in, __shfl_xor(m_in, 32));                                        \
      if (!__all(m_in - mrow[c] <= THR)) {                                             \
        float mn = fmaxf(mrow[c], m_in);                                               \
        float alpha = __expf(mrow[c] - mn);                                            \
        mrow[c] = mn;                                                                  \
        lrow[c] *= alpha;                                                              \
        f32x4 av;                                                                      \
        _Pragma("unroll")                                                              \
        for (int r = 0; r < 4; r++) av[r] = __shfl(alpha, l4 * 4 + r);                 \
        _Pragma("unroll")                                                              \
        for (int nf2 = 0; nf2 < 12; nf2++) o[c][nf2] *= av;                            \
      }                                                                                \
      float rs = 0.0f;                                                                 \
      _Pragma("unroll")                                                                \
      for (int nf = 0; nf < 4; nf++)                                                   \
        _Pragma("unroll")                                                              \
        for (int r = 0; r < 4; r++) {                                                  \
          float pv = __expf(s[c][nf][r] - mrow[c]);                                    \
          s[c][nf][r] = pv;                                                            \
          rs += pv;                                                                    \
        }                                                                              \
      rs += __shfl_xor(rs, 16);                                                        \
      rs += __shfl_xor(rs, 32);                                                        \
      lrow[c] += rs;                                                                   \
      uint32_t wq[8];                                                                  \
      _Pragma("unroll")                                                                \
      for (int nf = 0; nf < 4; nf++) {                                                 \
        wq[nf * 2 + 0] = pkbf(s[c][nf][0], s[c][nf][1]);                               \
        wq[nf * 2 + 1] = pkbf(s[c][nf][2], s[c][nf][3]);                               \
      }                                                                                \
      _Pragma("unroll")                                                                \
      for (int ks = 0; ks < 2; ks++) {                                                 \
        uint32_t A0 = __shfl(wq[(2 * ks) * 2 + 0], src0);                              \
        uint32_t A1 = __shfl(wq[(2 * ks) * 2 + 1], src0);                              \
        uint32_t B0 = __shfl(wq[(2 * ks + 1) * 2 + 0], src0);                          \
        uint32_t B1 = __shfl(wq[(2 * ks + 1) * 2 + 1], src0);                          \
        uint32_t C0w = __shfl(wq[(2 * ks) * 2 + 0], src1);                             \
        uint32_t C1w = __shfl(wq[(2 * ks) * 2 + 1], src1);                             \
        uint32_t D0 = __shfl(wq[(2 * ks + 1) * 2 + 0], src1);                          \
        uint32_t D1 = __shfl(wq[(2 * ks + 1) * 2 + 1], src1);                          \
        union { uint32_t u[4]; bf16x8 v; } fr;                                         \
        fr.u[0] = hibank ? B0 : A0;                                                    \
        fr.u[1] = hibank ? B1 : A1;                                                    \
        fr.u[2] = hibank ? D0 : C0w;                                                   \
        fr.u[3] = hibank ? D1 : C1w;                                                   \
        pa[c][ks] = fr.v;                                                              \
      }                                                                                \
    }

    SOFTMAX_CHUNK(1, rb, cb)
    if (act_a) SOFTMAX_CHUNK(0, ra, ca)
#undef SOFTMAX_CHUNK

    // O += P V   (A = in-register P frags, B = V from LDS)
#pragma unroll
    for (int ks = 0; ks < 2; ks++) {
#pragma unroll
      for (int nf2 = 0; nf2 < 12; nf2++) {
        int d = nf2 * 16 + l15;
        int cl = (ks * 4 + l4) ^ (d & 7);
        bf16x8 vb = *(const bf16x8*)(&sV[d][cl * 8]);
        o[1][nf2] = MFMA16(pa[1][ks], vb, o[1][nf2]);
        if (act_a) o[0][nf2] = MFMA16(pa[0][ks], vb, o[0][nf2]);
      }
    }

    __syncthreads();  // all waves done reading sK/sV
    if (pf) WRITE_TILES()
    __syncthreads();  // tile kt+1 visible
  }
#undef ISSUE_LOADS
#undef WRITE_TILES

  // epilogue: O/l -> ao (b*T+q, h*192+d), both chunks; l lives at lane l15=q
#pragma unroll
  for (int mf = 0; mf < 2; mf++) {
    const int rbase = (mf == 0) ? ra : rb;
#pragma unroll
    for (int r = 0; r < 4; r++) {
      float lv = __shfl(lrow[mf], l4 * 4 + r);
      float inv = 1.0f / lv;
      int qrow = rbase + l4 * 4 + r;
#pragma unroll
      for (int nf2 = 0; nf2 < 12; nf2++) {
        int d = nf2 * 16 + l15;
        ao[(size_t)(b * 2048 + qrow) * 3072 + h * 192 + d] = (bf16_t)(o[mf][nf2][r] * inv);
      }
    }
  }
}

// ----------------------------------------------------------------
extern "C" void kernel_launch(void* const* d_in, const int* in_sizes, int n_in,
                              void* d_out, int out_size, void* d_ws, size_t ws_size,
                              hipStream_t stream) {
  const float* x       = (const float*)d_in[0];
  const float* wq_down = (const float*)d_in[1];
  const float* wq_up   = (const float*)d_in[2];
  const float* wq_rope = (const float*)d_in[3];
  const float* wkv_down= (const float*)d_in[4];
  const float* wk_up   = (const float*)d_in[5];
  const float* wv_up   = (const float*)d_in[6];
  const float* wk_rope = (const float*)d_in[7];
  const float* wo      = (const float*)d_in[8];
  float* out = (float*)d_out;

  char* p = (char*)d_ws;
  auto take = [&](size_t elems) { bf16_t* r = (bf16_t*)p; p += elems * 2; return r; };
  bf16_t* xb    = take(4096ull * 2048);
  bf16_t* fw1   = take(3328ull * 2048);  // [wq_down(768) | wkv_down(512) | wq_rope(1024) | wk_rope(1024)]^T
  bf16_t* wqu_t = take(2048ull * 768);
  bf16_t* fw2   = take(5120ull * 512);   // [wk_up(2048) | wv_up(3072)]^T
  bf16_t* wo_t  = take(2048ull * 3072);
  bf16_t* qkvd  = take(4096ull * 1280);  // [q_down(768) | latent(512)]
  bf16_t* qbuf  = take(4096ull * 3072);
  bf16_t* kbuf  = take(4096ull * 3072);
  bf16_t* vbuf  = take(4096ull * 3072);
  bf16_t* vt    = take(4096ull * 3072);
  bf16_t* ao    = vbuf;  // v row-major dead after transpose_v; reuse for attention out

  dim3 tb(32, 8);
  cvt_f32_to_bf16<<<8192, 256, 0, stream>>>(x, xb);
  transpose_w<<<dim3(24, 64), tb, 0, stream>>>(wq_down,  fw1,                 2048, 768);
  transpose_w<<<dim3(16, 64), tb, 0, stream>>>(wkv_down, fw1 + 768ull * 2048, 2048, 512);
  transpose_w<<<dim3(32, 64), tb, 0, stream>>>(wq_rope,  fw1 + 1280ull * 2048,2048, 1024);
  transpose_w<<<dim3(32, 64), tb, 0, stream>>>(wk_rope,  fw1 + 2304ull * 2048,2048, 1024);
  transpose_w<<<dim3(64, 24), tb, 0, stream>>>(wq_up,    wqu_t,               768, 2048);
  transpose_w<<<dim3(64, 16), tb, 0, stream>>>(wk_up,    fw2,                 512, 2048);
  transpose_w<<<dim3(96, 16), tb, 0, stream>>>(wv_up,    fw2 + 2048ull * 512, 512, 3072);
  transpose_w<<<dim3(64, 96), tb, 0, stream>>>(wo,       wo_t,                3072, 2048);

  gemm_bt<4><<<dim3(26, 32), 256, 0, stream>>>(xb, 2048, fw1, qkvd, qbuf, kbuf, 2048, 0);
  gemm_bt<2><<<dim3(16, 32), 256, 0, stream>>>(qkvd, 1280, wqu_t, qbuf, nullptr, nullptr, 768, 0);
  gemm_bt<5><<<dim3(40, 32), 256, 0, stream>>>(qkvd + 768, 1280, fw2, kbuf, vbuf, nullptr, 512, 0);

  rope_inplace<<<8192, 256, 0, stream>>>(qbuf);
  rope_inplace<<<8192, 256, 0, stream>>>(kbuf);
  transpose_v_kernel<<<dim3(64, 6, 32), tb, 0, stream>>>(vbuf, vt);

  attn_kernel<<<512, 256, 0, stream>>>(qbuf, kbuf, vt, ao);

  gemm_bt<1><<<dim3(16, 32), 256, 0, stream>>>(ao, 3072, wo_t, out, nullptr, nullptr, 3072, 2048);
}

// Round 5
// 386.783 us; speedup vs baseline: 1.8928x; 1.8928x over previous
//
#include <hip/hip_runtime.h>
#include <hip/hip_bf16.h>
#include <cstdint>
#include <cstddef>

typedef __bf16 bf16_t;
typedef __bf16 bf16x8 __attribute__((ext_vector_type(8)));
typedef float f32x4 __attribute__((ext_vector_type(4)));

#define MFMA16(a, b, c) __builtin_amdgcn_mfma_f32_16x16x32_bf16((a), (b), (c), 0, 0, 0)

__device__ __forceinline__ void gload_lds16(const void* g, void* l) {
  __builtin_amdgcn_global_load_lds((__attribute__((address_space(1))) void*)(g),
                                   (__attribute__((address_space(3))) void*)(l),
                                   16, 0, 0);
}

__device__ __forceinline__ uint32_t pkbf(float lo, float hi) {
  union { bf16_t h[2]; uint32_t u; } u2;
  u2.h[0] = (bf16_t)lo; u2.h[1] = (bf16_t)hi;
  return u2.u;
}

// ---------------------------------------------------------------- cvt x fp32->bf16
__global__ __launch_bounds__(256) void cvt_f32_to_bf16(const float* __restrict__ in,
                                                       bf16_t* __restrict__ out) {
  size_t i = ((size_t)blockIdx.x * 256 + threadIdx.x) * 4;
  float4 v = *(const float4*)(in + i);
  bf16_t o0 = (bf16_t)v.x, o1 = (bf16_t)v.y, o2 = (bf16_t)v.z, o3 = (bf16_t)v.w;
  bf16_t o[4] = {o0, o1, o2, o3};
  *(uint2*)(out + i) = *(uint2*)o;
}

// ---------------------------------------------------------------- weight transpose fp32 (R,C) -> bf16 (C,R)
__global__ __launch_bounds__(256) void transpose_w(const float* __restrict__ in,
                                                   bf16_t* __restrict__ out, int R, int C) {
  __shared__ bf16_t tile[32][33];
  int c0 = blockIdx.x * 32, r0 = blockIdx.y * 32;
  int tx = threadIdx.x, ty = threadIdx.y;
#pragma unroll
  for (int s = 0; s < 4; s++) {
    int r = ty + s * 8;
    tile[r][tx] = (bf16_t)in[(size_t)(r0 + r) * C + c0 + tx];
  }
  __syncthreads();
#pragma unroll
  for (int s = 0; s < 4; s++) {
    int r = ty + s * 8;
    out[(size_t)(c0 + r) * R + r0 + tx] = tile[tx][r];
  }
}

// ---------------------------------------------------------------- v (4096,3072) -> vt (b,h,192,2048)
__global__ __launch_bounds__(256) void transpose_v_kernel(const bf16_t* __restrict__ v,
                                                          bf16_t* __restrict__ vt) {
  __shared__ bf16_t tile[32][33];
  int bh = blockIdx.z;
  int t0 = blockIdx.x * 32, d0 = blockIdx.y * 32;
  int tx = threadIdx.x, ty = threadIdx.y;
  const bf16_t* src = v + (size_t)(bh >> 4) * 2048 * 3072 + (bh & 15) * 192;
#pragma unroll
  for (int s = 0; s < 4; s++) {
    int t = ty + s * 8;
    tile[t][tx] = src[(size_t)(t0 + t) * 3072 + d0 + tx];
  }
  __syncthreads();
  bf16_t* dst = vt + (size_t)bh * 192 * 2048;
#pragma unroll
  for (int s = 0; s < 4; s++) {
    int d = ty + s * 8;
    dst[(size_t)(d0 + d) * 2048 + t0 + tx] = tile[tx][d];
  }
}

// ---------------------------------------------------------------- rope in-place on packed (4096, 16*192) buffer
__global__ __launch_bounds__(256) void rope_inplace(bf16_t* __restrict__ buf) {
  int idx = blockIdx.x * 256 + threadIdx.x;
  int j = idx & 31;
  int h = (idx >> 5) & 15;
  int row = idx >> 9;           // 0..4095
  int t = row & 2047;
  size_t base = (size_t)row * 3072 + h * 192 + 128;
  float inv = expf(-(float)j * 0.28782313662425574f);
  float ang = (float)t * inv;
  float c, s;
  sincosf(ang, &s, &c);
  float x1 = (float)buf[base + j];
  float x2 = (float)buf[base + j + 32];
  buf[base + j]      = (bf16_t)(x1 * c - x2 * s);
  buf[base + j + 32] = (bf16_t)(x1 * s + x2 * c);
}

// ---------------------------------------------------------------- GEMM: C = A(M,lda) [:, :K] * Bt(N,K)^T
template <int MODE>
__global__ __launch_bounds__(256) void gemm_bt(const bf16_t* __restrict__ A, int lda,
                                               const bf16_t* __restrict__ Bt,
                                               void* __restrict__ C0, void* __restrict__ C1,
                                               void* __restrict__ C2, int K, int ldc) {
  __shared__ __align__(16) bf16_t sA[128 * 64];
  __shared__ __align__(16) bf16_t sB[128 * 64];
  const int tid = threadIdx.x;
  const int l = tid & 63, w = tid >> 6;
  const int l15 = l & 15, l4 = l >> 4;
  const int wr = w >> 1, wc = w & 1;
  const int m0 = blockIdx.y * 128, n0 = blockIdx.x * 128;

  f32x4 acc[4][4] = {};

  for (int kt = 0; kt < K; kt += 64) {
#pragma unroll
    for (int r = 0; r < 4; r++) {
      int i = r * 256 + tid;
      int row = i >> 3, cl = i & 7;
      int cg = cl ^ (row & 7);  // pre-swizzled global source, linear LDS dest
      const bf16_t* srcA = A + (size_t)(m0 + row) * lda + kt + cg * 8;
      const bf16_t* srcB = Bt + (size_t)(n0 + row) * K + kt + cg * 8;
      char* dstA = (char*)sA + (size_t)(r * 256 + w * 64) * 16;
      char* dstB = (char*)sB + (size_t)(r * 256 + w * 64) * 16;
      gload_lds16(srcA, dstA);
      gload_lds16(srcB, dstB);
    }
    __syncthreads();
#pragma unroll
    for (int ks = 0; ks < 2; ks++) {
      bf16x8 af[4], bfr[4];
#pragma unroll
      for (int mf = 0; mf < 4; mf++) {
        int row = wr * 64 + mf * 16 + l15;
        int cl = (ks * 4 + l4) ^ (row & 7);
        af[mf] = *(const bf16x8*)(sA + row * 64 + cl * 8);
      }
#pragma unroll
      for (int nf = 0; nf < 4; nf++) {
        int row = wc * 64 + nf * 16 + l15;
        int cl = (ks * 4 + l4) ^ (row & 7);
        bfr[nf] = *(const bf16x8*)(sB + row * 64 + cl * 8);
      }
#pragma unroll
      for (int mf = 0; mf < 4; mf++)
#pragma unroll
        for (int nf = 0; nf < 4; nf++)
          acc[mf][nf] = MFMA16(af[mf], bfr[nf], acc[mf][nf]);
    }
    __syncthreads();
  }

#pragma unroll
  for (int mf = 0; mf < 4; mf++)
#pragma unroll
    for (int nf = 0; nf < 4; nf++)
#pragma unroll
      for (int r = 0; r < 4; r++) {
        int m = m0 + wr * 64 + mf * 16 + l4 * 4 + r;
        int n = n0 + wc * 64 + nf * 16 + l15;
        float v = acc[mf][nf][r];
        if constexpr (MODE == 1) {
          ((float*)C0)[(size_t)m * ldc + n] = v;
        } else if constexpr (MODE == 2) {
          ((bf16_t*)C0)[(size_t)m * 3072 + (n >> 7) * 192 + (n & 127)] = (bf16_t)v;
        } else if constexpr (MODE == 4) {
          if (n < 1280) {
            ((bf16_t*)C0)[(size_t)m * 1280 + n] = (bf16_t)v;
          } else if (n < 2304) {
            int nn = n - 1280;
            ((bf16_t*)C1)[(size_t)m * 3072 + (nn >> 6) * 192 + 128 + (nn & 63)] = (bf16_t)v;
          } else {
            int nn = n - 2304;
            ((bf16_t*)C2)[(size_t)m * 3072 + (nn >> 6) * 192 + 128 + (nn & 63)] = (bf16_t)v;
          }
        } else {  // MODE 5
          if (n < 2048) {
            ((bf16_t*)C0)[(size_t)m * 3072 + (n >> 7) * 192 + (n & 127)] = (bf16_t)v;
          } else {
            ((bf16_t*)C1)[(size_t)m * 3072 + (n - 2048)] = (bf16_t)v;
          }
        }
      }
}

// ---------------------------------------------------------------- flash attention (causal)
// 512 threads / 8 waves, 128-row q-chunks paired (c, 15-c), KV tile 64 double-buffered
// in LDS via global_load_lds (T3 2-phase: issue next tile's loads, compute current,
// one __syncthreads whose vmcnt-drain lands after compute). Swapped QK^T softmax.
__global__ __launch_bounds__(512, 2) void attn_kernel(const bf16_t* __restrict__ q,
                                                      const bf16_t* __restrict__ kbuf,
                                                      const bf16_t* __restrict__ vt,
                                                      bf16_t* __restrict__ ao) {
  __shared__ __align__(16) bf16_t sK[2][64][192];  // perm-24 swizzle, dbuf
  __shared__ __align__(16) bf16_t sV[2][192][64];  // xor-8 chunk swizzle, dbuf

  const int tid = threadIdx.x, l = tid & 63, w = tid >> 6;
  const int l15 = l & 15, l4 = (l >> 4) & 3;
  const int bh = blockIdx.x & 31;            // same-bh blocks land on same XCD (i%8 preserved)
  const int c = blockIdx.x >> 5;             // pair index 0..7
  const int b = bh >> 4, h = bh & 15;
  const int ca = c, cb = 15 - c;             // 128-row chunks
  const int ra = ca * 128 + w * 16;
  const int rb = cb * 128 + w * 16;
  const int tga = 2 * ca + (w >> 2);         // diag k-tile for this wave's chunk-a rows
  const int tgb = 2 * cb + (w >> 2);

  const bf16_t* qp = q + (size_t)b * 2048 * 3072 + h * 192;
  const bf16_t* kp = kbuf + (size_t)b * 2048 * 3072 + h * 192;
  const bf16_t* vp = vt + (size_t)bh * 192 * 2048;

  bf16x8 qf[2][6];
#pragma unroll
  for (int kd = 0; kd < 6; kd++) {
    qf[0][kd] = *(const bf16x8*)(qp + (size_t)(ra + l15) * 3072 + kd * 32 + l4 * 8);
    qf[1][kd] = *(const bf16x8*)(qp + (size_t)(rb + l15) * 3072 + kd * 32 + l4 * 8);
  }

  f32x4 o[2][12] = {};
  float mrow[2] = {-__builtin_inff(), -__builtin_inff()};
  float lrow[2] = {0.0f, 0.0f};

  const float scale = 0.07216878364870322f;  // 1/sqrt(192)
  const float THR = 7.0f;                    // defer-max threshold
  const int nkt = 2 * cb + 2;
  const int src0 = l15 + ((l4 & 1) << 5);
  const int src1 = src0 + 16;
  const bool hibank = (l4 & 2) != 0;

  // stage tile KT into buffer BB (6 gload_lds per thread, zero VGPR cost)
#define STAGE(BB, KT)                                                               \
  {                                                                                 \
    const int k0s = (KT) * 64;                                                      \
    _Pragma("unroll")                                                               \
    for (int r = 0; r < 3; r++) {                                                   \
      int i = r * 512 + tid;                                                        \
      int row = i / 24, cc = i % 24;                                                \
      int g = cc - (row & 7) * 3;                                                   \
      if (g < 0) g += 24;                                                           \
      gload_lds16(kp + (size_t)(k0s + row) * 3072 + g * 8,                          \
                  (char*)&sK[BB][0][0] + (size_t)(r * 512 + w * 64) * 16);          \
    }                                                                               \
    _Pragma("unroll")                                                               \
    for (int r = 0; r < 3; r++) {                                                   \
      int i = r * 512 + tid;                                                        \
      int d = i >> 3, cc = i & 7;                                                   \
      gload_lds16(vp + (size_t)d * 2048 + k0s + (cc ^ (d & 7)) * 8,                 \
                  (char*)&sV[BB][0][0] + (size_t)(r * 512 + w * 64) * 16);          \
    }                                                                               \
  }

  STAGE(0, 0)
  __syncthreads();  // vmcnt(0) drained by compiler -> tile 0 ready

  for (int kt = 0; kt < nkt; kt++) {
    const int bb = kt & 1;
    const int k0 = kt * 64;
    const bool act_a = (kt <= tga);
    const bool act_b = (kt <= tgb);
    if (kt + 1 < nkt) STAGE(bb ^ 1, kt + 1)  // in flight during this tile's compute

    // S^T = K Q^T  (swapped operands)
    f32x4 s[2][4] = {};
#pragma unroll
    for (int kd = 0; kd < 6; kd++) {
      bf16x8 bk[4];
#pragma unroll
      for (int nf = 0; nf < 4; nf++) {
        int row = nf * 16 + l15;
        int cl = kd * 4 + l4 + (row & 7) * 3;
        if (cl >= 24) cl -= 24;
        bk[nf] = *(const bf16x8*)(&sK[bb][row][cl * 8]);
      }
      if (act_b) {
#pragma unroll
        for (int nf = 0; nf < 4; nf++)
          s[1][nf] = MFMA16(bk[nf], qf[1][kd], s[1][nf]);
      }
      if (act_a) {
#pragma unroll
        for (int nf = 0; nf < 4; nf++)
          s[0][nf] = MFMA16(bk[nf], qf[0][kd], s[0][nf]);
      }
    }

    bf16x8 pa[2][2] = {};

#define SOFTMAX_CHUNK(c, rbase, tg)                                                    \
    {                                                                                  \
      const bool diag = (kt == (tg));                                                  \
      _Pragma("unroll")                                                                \
      for (int nf = 0; nf < 4; nf++)                                                   \
        _Pragma("unroll")                                                              \
        for (int r = 0; r < 4; r++) {                                                  \
          float sv = s[c][nf][r] * scale;                                              \
          if (diag) {                                                                  \
            int ktok = k0 + nf * 16 + l4 * 4 + r;                                      \
            if (ktok > (rbase) + l15) sv = -__builtin_inff();                          \
          }                                                                            \
          s[c][nf][r] = sv;                                                            \
        }                                                                              \
      float m_in = s[c][0][0];                                                         \
      _Pragma("unroll")                                                                \
      for (int nf = 0; nf < 4; nf++)                                                   \
        _Pragma("unroll")                                                              \
        for (int r = 0; r < 4; r++)                                                    \
          if (nf | r) m_in = fmaxf(m_in, s[c][nf][r]);                                 \
      m_in = fmaxf(m_in, __shfl_xor(m_in, 16));                                        \
      m_in = fmaxf(m_in, __shfl_xor(m_in, 32));                                        \
      if (!__all(m_in - mrow[c] <= THR)) {                                             \
        float mn = fmaxf(mrow[c], m_in);                                               \
        float alpha = __expf(mrow[c] - mn);                                            \
        mrow[c] = mn;                                                                  \
        lrow[c] *= alpha;                                                              \
        f32x4 av;                                                                      \
        _Pragma("unroll")                                                              \
        for (int r = 0; r < 4; r++) av[r] = __shfl(alpha, l4 * 4 + r);                 \
        _Pragma("unroll")                                                              \
        for (int nf2 = 0; nf2 < 12; nf2++) o[c][nf2] *= av;                            \
      }                                                                                \
      float rs = 0.0f;                                                                 \
      _Pragma("unroll")                                                                \
      for (int nf = 0; nf < 4; nf++)                                                   \
        _Pragma("unroll")                                                              \
        for (int r = 0; r < 4; r++) {                                                  \
          float pv = __expf(s[c][nf][r] - mrow[c]);                                    \
          s[c][nf][r] = pv;                                                            \
          rs += pv;                                                                    \
        }                                                                              \
      rs += __shfl_xor(rs, 16);                                                        \
      rs += __shfl_xor(rs, 32);                                                        \
      lrow[c] += rs;                                                                   \
      uint32_t wq[8];                                                                  \
      _Pragma("unroll")                                                                \
      for (int nf = 0; nf < 4; nf++) {                                                 \
        wq[nf * 2 + 0] = pkbf(s[c][nf][0], s[c][nf][1]);                               \
        wq[nf * 2 + 1] = pkbf(s[c][nf][2], s[c][nf][3]);                               \
      }                                                                                \
      _Pragma("unroll")                                                                \
      for (int ks = 0; ks < 2; ks++) {                                                 \
        uint32_t A0 = __shfl(wq[(2 * ks) * 2 + 0], src0);                              \
        uint32_t A1 = __shfl(wq[(2 * ks) * 2 + 1], src0);                              \
        uint32_t B0 = __shfl(wq[(2 * ks + 1) * 2 + 0], src0);                          \
        uint32_t B1 = __shfl(wq[(2 * ks + 1) * 2 + 1], src0);                          \
        uint32_t C0w = __shfl(wq[(2 * ks) * 2 + 0], src1);                             \
        uint32_t C1w = __shfl(wq[(2 * ks) * 2 + 1], src1);                             \
        uint32_t D0 = __shfl(wq[(2 * ks + 1) * 2 + 0], src1);                          \
        uint32_t D1 = __shfl(wq[(2 * ks + 1) * 2 + 1], src1);                          \
        union { uint32_t u[4]; bf16x8 v; } fr;                                         \
        fr.u[0] = hibank ? B0 : A0;                                                    \
        fr.u[1] = hibank ? B1 : A1;                                                    \
        fr.u[2] = hibank ? D0 : C0w;                                                   \
        fr.u[3] = hibank ? D1 : C1w;                                                   \
        pa[c][ks] = fr.v;                                                              \
      }                                                                                \
    }

    if (act_b) SOFTMAX_CHUNK(1, rb, tgb)
    if (act_a) SOFTMAX_CHUNK(0, ra, tga)
#undef SOFTMAX_CHUNK

    // O += P V   (A = in-register P frags, B = V from LDS)
#pragma unroll
    for (int ks = 0; ks < 2; ks++) {
#pragma unroll
      for (int nf2 = 0; nf2 < 12; nf2++) {
        int d = nf2 * 16 + l15;
        int cl = (ks * 4 + l4) ^ (d & 7);
        bf16x8 vb = *(const bf16x8*)(&sV[bb][d][cl * 8]);
        if (act_b) o[1][nf2] = MFMA16(pa[1][ks], vb, o[1][nf2]);
        if (act_a) o[0][nf2] = MFMA16(pa[0][ks], vb, o[0][nf2]);
      }
    }

    __syncthreads();  // drains vmcnt(0) (tile kt+1 landed) + read-done on buf bb
  }
#undef STAGE

  // epilogue: O/l -> ao (b*T+q, h*192+d), both chunks; l lives at lane l15=q
#pragma unroll
  for (int mf = 0; mf < 2; mf++) {
    const int rbase = (mf == 0) ? ra : rb;
#pragma unroll
    for (int r = 0; r < 4; r++) {
      float lv = __shfl(lrow[mf], l4 * 4 + r);
      float inv = 1.0f / lv;
      int qrow = rbase + l4 * 4 + r;
#pragma unroll
      for (int nf2 = 0; nf2 < 12; nf2++) {
        int d = nf2 * 16 + l15;
        ao[(size_t)(b * 2048 + qrow) * 3072 + h * 192 + d] = (bf16_t)(o[mf][nf2][r] * inv);
      }
    }
  }
}

// ----------------------------------------------------------------
extern "C" void kernel_launch(void* const* d_in, const int* in_sizes, int n_in,
                              void* d_out, int out_size, void* d_ws, size_t ws_size,
                              hipStream_t stream) {
  const float* x       = (const float*)d_in[0];
  const float* wq_down = (const float*)d_in[1];
  const float* wq_up   = (const float*)d_in[2];
  const float* wq_rope = (const float*)d_in[3];
  const float* wkv_down= (const float*)d_in[4];
  const float* wk_up   = (const float*)d_in[5];
  const float* wv_up   = (const float*)d_in[6];
  const float* wk_rope = (const float*)d_in[7];
  const float* wo      = (const float*)d_in[8];
  float* out = (float*)d_out;

  char* p = (char*)d_ws;
  auto take = [&](size_t elems) { bf16_t* r = (bf16_t*)p; p += elems * 2; return r; };
  bf16_t* xb    = take(4096ull * 2048);
  bf16_t* fw1   = take(3328ull * 2048);  // [wq_down(768) | wkv_down(512) | wq_rope(1024) | wk_rope(1024)]^T
  bf16_t* wqu_t = take(2048ull * 768);
  bf16_t* fw2   = take(5120ull * 512);   // [wk_up(2048) | wv_up(3072)]^T
  bf16_t* wo_t  = take(2048ull * 3072);
  bf16_t* qkvd  = take(4096ull * 1280);  // [q_down(768) | latent(512)]
  bf16_t* qbuf  = take(4096ull * 3072);
  bf16_t* kbuf  = take(4096ull * 3072);
  bf16_t* vbuf  = take(4096ull * 3072);
  bf16_t* vt    = take(4096ull * 3072);
  bf16_t* ao    = vbuf;  // v row-major dead after transpose_v; reuse for attention out

  dim3 tb(32, 8);
  cvt_f32_to_bf16<<<8192, 256, 0, stream>>>(x, xb);
  transpose_w<<<dim3(24, 64), tb, 0, stream>>>(wq_down,  fw1,                 2048, 768);
  transpose_w<<<dim3(16, 64), tb, 0, stream>>>(wkv_down, fw1 + 768ull * 2048, 2048, 512);
  transpose_w<<<dim3(32, 64), tb, 0, stream>>>(wq_rope,  fw1 + 1280ull * 2048,2048, 1024);
  transpose_w<<<dim3(32, 64), tb, 0, stream>>>(wk_rope,  fw1 + 2304ull * 2048,2048, 1024);
  transpose_w<<<dim3(64, 24), tb, 0, stream>>>(wq_up,    wqu_t,               768, 2048);
  transpose_w<<<dim3(64, 16), tb, 0, stream>>>(wk_up,    fw2,                 512, 2048);
  transpose_w<<<dim3(96, 16), tb, 0, stream>>>(wv_up,    fw2 + 2048ull * 512, 512, 3072);
  transpose_w<<<dim3(64, 96), tb, 0, stream>>>(wo,       wo_t,                3072, 2048);

  gemm_bt<4><<<dim3(26, 32), 256, 0, stream>>>(xb, 2048, fw1, qkvd, qbuf, kbuf, 2048, 0);
  gemm_bt<2><<<dim3(16, 32), 256, 0, stream>>>(qkvd, 1280, wqu_t, qbuf, nullptr, nullptr, 768, 0);
  gemm_bt<5><<<dim3(40, 32), 256, 0, stream>>>(qkvd + 768, 1280, fw2, kbuf, vbuf, nullptr, 512, 0);

  rope_inplace<<<8192, 256, 0, stream>>>(qbuf);
  rope_inplace<<<8192, 256, 0, stream>>>(kbuf);
  transpose_v_kernel<<<dim3(64, 6, 32), tb, 0, stream>>>(vbuf, vt);

  attn_kernel<<<256, 512, 0, stream>>>(qbuf, kbuf, vt, ao);

  gemm_bt<1><<<dim3(16, 32), 256, 0, stream>>>(ao, 3072, wo_t, out, nullptr, nullptr, 3072, 2048);
}